// Round 5
// baseline (317.027 us; speedup 1.0000x reference)
//
#include <hip/hip_runtime.h>
#include <stdint.h>

typedef unsigned short ushort_t;
typedef __attribute__((ext_vector_type(8))) short bf16x8;   // 8 bf16 = 4 VGPRs (MFMA A/B frag)
typedef __attribute__((ext_vector_type(4))) float f32x4;    // MFMA C/D frag / fp32 vec-load

#define BM 256
#define BN 256
#define BK 64
#define SCALING 2.0f

static __device__ __forceinline__ unsigned short f2b(float f) {
    union { float f; unsigned int i; } v;
    v.f = f;
    unsigned int r = 0x7FFFu + ((v.i >> 16) & 1u);   // round-to-nearest-even
    return (unsigned short)((v.i + r) >> 16);
}

// async global->LDS, 16 bytes/lane. HW dest = wave-uniform base + lane*16.
static __device__ __forceinline__ void ld_g2l16(const void* g, void* l) {
    __builtin_amdgcn_global_load_lds(
        (const __attribute__((address_space(1))) void*)g,
        (__attribute__((address_space(3))) void*)l,
        16, 0, 0);
}

#define SFENCE()     __builtin_amdgcn_sched_barrier(0)
#define BARRIER()    do { SFENCE(); __builtin_amdgcn_s_barrier(); SFENCE(); } while (0)
#define WAIT_LGKM0() do { asm volatile("s_waitcnt lgkmcnt(0)" ::: "memory"); SFENCE(); } while (0)
#define WAIT_VM(N)   do { asm volatile("s_waitcnt vmcnt(" #N ")" ::: "memory"); SFENCE(); } while (0)

// ---------------------------------------------------------------------------
// Kernel 1: W_eff[o][d] = W[o][d] + SCALING * sum_r B[o][r]*A[r][d]  (fp32 in, bf16 out RNE)
// ---------------------------------------------------------------------------
__global__ void weff_kernel(const float* __restrict__ W,
                            const float* __restrict__ A,
                            const float* __restrict__ Bm,
                            ushort_t* __restrict__ Weff,
                            int D, int R) {
    int gid = blockIdx.x * blockDim.x + threadIdx.x;
    int perRow = D >> 3;
    if (gid >= D * perRow) return;
    int o  = gid / perRow;
    int d0 = (gid - o * perRow) << 3;

    float br[16];
    for (int r = 0; r < R; ++r) br[r] = SCALING * Bm[(size_t)o * R + r];

    float acc[8];
    #pragma unroll
    for (int j = 0; j < 8; ++j) acc[j] = W[(size_t)o * D + d0 + j];
    for (int r = 0; r < R; ++r) {
        #pragma unroll
        for (int j = 0; j < 8; ++j) acc[j] += br[r] * A[(size_t)r * D + d0 + j];
    }
    union { bf16x8 v; unsigned short s[8]; } ov;
    #pragma unroll
    for (int j = 0; j < 8; ++j) ov.s[j] = f2b(acc[j]);
    *(bf16x8*)(Weff + (size_t)o * D + d0) = ov.v;
}

// ---------------------------------------------------------------------------
// Fused GEMM: Y[m][n] = sum_k X_f32[m][k]*Wt_bf16[n][k] + bias[n]
//   R1's 2-barrier structure (measured best: 89us, 31% MfmaUtil) + fused
//   fp32->bf16 A-conversion with FULL-ITERATION prefetch distances.
//   Root cause of R3/R4 regressions: A reg-staging drained in the same
//   iteration it was issued (exposed loaded-HBM latency each iter, all
//   waves lockstep-stalled). Here every consume is >= 1 iteration after
//   its issue, and the steady loop has NO explicit vmcnt at all.
//
//   Per iter t (read buf = sA/sB[t&1]):
//      1st half: ds_read bF0(s0), bF1(s1), aF(s0); MFMA ks0;
//               re-read aF(s1) into the SAME regs (WAR via compiler deps;
//               pays for aStage's 32 VGPRs);
//               lgkm0 + BARRIER  (all reads of both bufs done -> free)
//     2nd half: stage B(t+2) -> sB[t&1] (4 gload_lds, fire-and-forget)
//               cvt aStage (=A(t+2), loaded iter t-1) -> write sA[t&1]
//                 [compiler's implicit vmcnt here retires A(t+2) (1 iter
//                  old) and B(t+1) (1 iter old) -- both landed; this is
//                  the ONLY steady-state vm wait]
//               issue A(t+3) -> aStage (8 dwordx4; consumed iter t+1)
//               MFMA ks1; lgkm0 + BARRIER
//   Race audit: sA[t&1] writes (2nd half) vs all waves' sA[t&1] reads
//   (1st half) separated by the mid barrier. Visibility of cvt writes to
//   iter t+2 readers via s8 lgkm0+barrier. Tail: one vmcnt(0) at t=nt-2.
// ---------------------------------------------------------------------------
static __device__ __forceinline__ void mfma32(const bf16x8 (&aF)[8], const bf16x8 (&bF)[4],
                                              f32x4 (&acc)[8][4]) {
    __builtin_amdgcn_s_setprio(1);
    #pragma unroll
    for (int i = 0; i < 8; ++i)
        #pragma unroll
        for (int j = 0; j < 4; ++j)
            acc[i][j] = __builtin_amdgcn_mfma_f32_16x16x32_bf16(aF[i], bF[j], acc[i][j], 0, 0, 0);
    __builtin_amdgcn_s_setprio(0);
}

template<int Q>
static __device__ __forceinline__ void cvt_write(const f32x4 (&src)[8], ushort_t* nA, int tid) {
    union { bf16x8 v; unsigned short s[8]; } pk;
    #pragma unroll
    for (int e = 0; e < 4; ++e) pk.s[e]     = f2b(src[2 * Q][e]);
    #pragma unroll
    for (int e = 0; e < 4; ++e) pk.s[4 + e] = f2b(src[2 * Q + 1][e]);
    *(bf16x8*)(nA + tid * 8 + Q * 4096) = pk.v;
}

static __device__ __forceinline__ void cvt_write_all(const f32x4 (&src)[8], ushort_t* nA, int tid) {
    cvt_write<0>(src, nA, tid);
    cvt_write<1>(src, nA, tid);
    cvt_write<2>(src, nA, tid);
    cvt_write<3>(src, nA, tid);
}

static __device__ __forceinline__ void load_a(const float* ga, f32x4 (&dst)[8], int K) {
    #pragma unroll
    for (int q = 0; q < 4; ++q) {
        dst[2 * q]     = *(const f32x4*)(ga + (size_t)(q * 64) * K);
        dst[2 * q + 1] = *(const f32x4*)(ga + (size_t)(q * 64) * K + 4);
    }
}

__global__ __launch_bounds__(512, 2) void gemm_fused(
    const float*    __restrict__ X,     // [M,K] fp32
    const ushort_t* __restrict__ Wt,    // [N,K] bf16 (Weff)
    const float*    __restrict__ bias,  // [N]   fp32
    float*          __restrict__ Y,     // [M,N] fp32
    int M, int N, int K)
{
    __shared__ __align__(16) ushort_t sA[2][BM * BK];   // 2 x 32 KB
    __shared__ __align__(16) ushort_t sB[2][BN * BK];   // 2 x 32 KB

    const int tid  = threadIdx.x;
    const int lane = tid & 63;
    const int wave = tid >> 6;
    const int wm   = wave >> 2;          // 0..1  -> rows [wm*128, +128)
    const int wn   = wave & 3;           // 0..3  -> cols [wn*64,  +64)

    // ---- XCD-aware tile assignment ----
    const int nT = N / BN;
    const int mT = M / BM;
    int mTile, nTile;
    if (((mT * nT) & 7) == 0 && (((mT * nT) >> 3) % nT) == 0) {
        const int xcd = blockIdx.x & 7;
        const int loc = blockIdx.x >> 3;
        const int mPerXcd = ((mT * nT) >> 3) / nT;
        mTile = xcd * mPerXcd + loc / nT;
        nTile = loc % nT;
    } else {
        nTile = blockIdx.x % nT;
        mTile = blockIdx.x / nT;
    }
    const int mBase = mTile * BM;
    const int nBase = nTile * BN;

    // ---- staging map: thread tid owns cell (row = tid>>3 + q*64, slot = tid&7);
    //      slot s of row r holds chunk s^(r&7)  (r&7 invariant under +64)
    const int sRow   = tid >> 3;
    const int sChunk = (tid & 7) ^ (sRow & 7);
    const float*    gA = X  + (size_t)(mBase + sRow) * K + sChunk * 8;
    const ushort_t* gB = Wt + (size_t)(nBase + sRow) * K + sChunk * 8;

    // ---- fragment read addressing ----
    const int fRow  = lane & 15;
    const int g     = lane >> 4;
    const int aBase = (wm * 128 + fRow) * BK;
    const int bBase = (wn * 64  + fRow) * BK;
    const int s0    = ((0 + g) ^ (lane & 7)) * 8;
    const int s1    = ((4 + g) ^ (lane & 7)) * 8;

    f32x4 acc[8][4];
    #pragma unroll
    for (int i = 0; i < 8; ++i)
        #pragma unroll
        for (int j = 0; j < 4; ++j)
            acc[i][j] = (f32x4){0.f, 0.f, 0.f, 0.f};

    f32x4 aStage[8];                              // 32 VGPR: A(t+3) fp32 in flight
    const int nt = K / BK;

    // ---- prologue ----
    // issue A(0)->aStage, A(1)->aTmp, B(0)->sB[0], B(1)->sB[1];
    // cvt A(0)->sA[0] (vmcnt retires A0, B's fly); cvt A(1)->sA[1] (retires A1);
    // issue A(2)->aStage; drain B(0); lgkm0; barrier.
    {
        f32x4 aTmp[8];                            // prologue-only; reuses frag regs
        load_a(gA, aStage, K);
        load_a(gA + BK, aTmp, K);
        #pragma unroll
        for (int q = 0; q < 4; ++q)
            ld_g2l16(gB + (size_t)(q * 64) * K, &sB[0][0] + tid * 8 + q * 4096);
        #pragma unroll
        for (int q = 0; q < 4; ++q)
            ld_g2l16(gB + BK + (size_t)(q * 64) * K, &sB[1][0] + tid * 8 + q * 4096);
        cvt_write_all(aStage, &sA[0][0], tid);    // implicit vmcnt retires A(0)
        cvt_write_all(aTmp,   &sA[1][0], tid);    // implicit vmcnt retires A(1)
        if (nt > 2) {
            load_a(gA + 2 * BK, aStage, K);
            WAIT_VM(12);                          // retire B(0); B(1)+A(2) fly
        } else {
            WAIT_VM(4);                           // retire B(0); B(1) flies
        }
        WAIT_LGKM0();
        BARRIER();
    }

    for (int t = 0; t < nt; ++t) {
        const ushort_t* pA = &sA[t & 1][0];
        const ushort_t* pB = &sB[t & 1][0];

        // ---- first half: all LDS reads of both current buffers ----
        bf16x8 aF[8], bF0[4], bF1[4];
        #pragma unroll
        for (int j = 0; j < 4; ++j) bF0[j] = *(const bf16x8*)(pB + bBase + j * (16 * BK) + s0);
        #pragma unroll
        for (int j = 0; j < 4; ++j) bF1[j] = *(const bf16x8*)(pB + bBase + j * (16 * BK) + s1);
        #pragma unroll
        for (int i = 0; i < 8; ++i) aF[i] = *(const bf16x8*)(pA + aBase + i * (16 * BK) + s0);

        mfma32(aF, bF0, acc);                     // ks0

        #pragma unroll
        for (int i = 0; i < 8; ++i) aF[i] = *(const bf16x8*)(pA + aBase + i * (16 * BK) + s1);

        WAIT_LGKM0();     // this wave's reads of sA/sB[t&1] complete
        BARRIER();        // ... for every wave -> both buffers free to overwrite

        // ---- second half: staging (1-iter distances) + ks1 ----
        if (t + 2 < nt) {
            ushort_t* lBn = &sB[t & 1][0] + tid * 8;
            #pragma unroll
            for (int q = 0; q < 4; ++q)
                ld_g2l16(gB + (size_t)(t + 2) * BK + (size_t)(q * 64) * K, lBn + q * 4096);
            // cvt A(t+2) (loaded iter t-1) -> sA[t&1]; the compiler's implicit
            // vmcnt here retires A(t+2)+B(t+1), both >=1 iteration old.
            cvt_write_all(aStage, &sA[t & 1][0], tid);
        }
        if (t + 3 < nt)
            load_a(gA + (size_t)(t + 3) * BK, aStage, K);

        mfma32(aF, bF1, acc);                     // ks1

        if (t == nt - 2) { WAIT_VM(0); }          // tail: drain B(nt-1)
        if (t + 1 < nt)  { WAIT_LGKM0(); BARRIER(); }
    }

    // ---- epilogue: C/D layout col(n)=lane&15, row(m)=(lane>>4)*4+reg ----
    const int col  = lane & 15;
    const int rowq = (lane >> 4) * 4;
    #pragma unroll
    for (int j = 0; j < 4; ++j) {
        const int n    = nBase + wn * 64 + j * 16 + col;
        const float bv = bias[n];
        #pragma unroll
        for (int i = 0; i < 8; ++i) {
            const int mRow = mBase + wm * 128 + i * 16 + rowq;
            #pragma unroll
            for (int r = 0; r < 4; ++r)
                Y[(size_t)(mRow + r) * N + n] = acc[i][j][r] + bv;
        }
    }
}

// ---------------------------------------------------------------------------
// Fallback (only if ws too small / shapes odd): correct fused fp32 kernel.
// ---------------------------------------------------------------------------
__global__ __launch_bounds__(256) void fused_naive(
    const float* __restrict__ x, const float* __restrict__ W,
    const float* __restrict__ b, const float* __restrict__ A,
    const float* __restrict__ Bm, float* __restrict__ y, int D, int R)
{
    extern __shared__ float smem[];
    float* sx  = smem;
    float* red = smem + D;
    float* sh  = red + 256;
    const int tid = threadIdx.x;
    const int m   = blockIdx.x;

    for (int i = tid; i < D; i += 256) sx[i] = x[(size_t)m * D + i];
    __syncthreads();

    for (int r = 0; r < R; ++r) {
        float p = 0.f;
        for (int k = tid; k < D; k += 256) p += sx[k] * A[(size_t)r * D + k];
        red[tid] = p; __syncthreads();
        for (int s = 128; s > 0; s >>= 1) {
            if (tid < s) red[tid] += red[tid + s];
            __syncthreads();
        }
        if (tid == 0) sh[r] = red[0];
        __syncthreads();
    }

    for (int n = tid; n < D; n += 256) {
        float base = 0.f;
        const float* wr = W + (size_t)n * D;
        for (int k = 0; k < D; ++k) base += sx[k] * wr[k];
        float lora = 0.f;
        for (int r = 0; r < R; ++r) lora += sh[r] * Bm[(size_t)n * R + r];
        y[(size_t)m * D + n] = base + b[n] + SCALING * lora;
    }
}

extern "C" void kernel_launch(void* const* d_in, const int* in_sizes, int n_in,
                              void* d_out, int out_size, void* d_ws, size_t ws_size,
                              hipStream_t stream) {
    const float* x  = (const float*)d_in[0];
    const float* W  = (const float*)d_in[1];
    const float* b  = (const float*)d_in[2];
    const float* A  = (const float*)d_in[3];
    const float* Bm = (const float*)d_in[4];
    float* y = (float*)d_out;

    const int D = in_sizes[2];                 // 1024
    const int R = in_sizes[3] / D;             // 8
    const int M = in_sizes[0] / D;             // 32768
    (void)n_in; (void)out_size;

    const size_t weffBytes = (size_t)D * D * sizeof(ushort_t);   // 2 MB

    if (ws_size >= weffBytes &&
        (D % BN) == 0 && (M % BM) == 0 && (D % BK) == 0 && (D / BK) >= 2) {
        ushort_t* Weff = (ushort_t*)d_ws;

        int wthreads = D * (D / 8);
        weff_kernel<<<dim3((wthreads + 255) / 256), 256, 0, stream>>>(W, A, Bm, Weff, D, R);

        dim3 grid((M / BM) * (D / BN));        // 1D; kernel does XCD-aware remap
        gemm_fused<<<grid, 512, 0, stream>>>(x, Weff, b, y, M, D, D);
    } else {
        size_t shmem = (size_t)(D + 256 + R) * sizeof(float);
        fused_naive<<<dim3(M), 256, shmem, stream>>>(x, W, b, A, Bm, y, D, R);
    }
}